// Round 4
// baseline (8378.783 us; speedup 1.0000x reference)
//
#include <hip/hip_runtime.h>
#include <hip/hip_bf16.h>

#define TMAX 4096

__device__ __forceinline__ float fexp2(float x){ return __builtin_amdgcn_exp2f(x); }
__device__ __forceinline__ float frcp (float x){ return __builtin_amdgcn_rcpf(x); }

// tanh(x) = 1 - 2/(exp2(2x*log2e)+1)   (saturates correctly for |x| large)
__device__ __forceinline__ float ftanh(float x){
    return 1.0f - 2.0f * frcp(fexp2(x * 2.8853900817779268f) + 1.0f);
}
// sigmoid(x) = 1/(1+exp2(-x*log2e))
__device__ __forceinline__ float fsigm(float x){
    return frcp(1.0f + fexp2(x * -1.4426950408889634f));
}

// x += value from lane (lane ^ xor) within each 32-lane group.
// ds_swizzle bit-mode: offset = (xor<<10) | (or<<5) | and, and=0x1F.
template<int OFF>
__device__ __forceinline__ float swz_add(float x){
    int t = __builtin_amdgcn_ds_swizzle(__float_as_int(x), OFF);
    return x + __int_as_float(t);
}

__global__ __launch_bounds__(64, 1)
void ode_rk4_kernel(const float* __restrict__ s_grid,
                    const float* __restrict__ y0,
                    const float* __restrict__ W1,
                    const float* __restrict__ b1,
                    const float* __restrict__ W2,
                    const float* __restrict__ b2,
                    const float* __restrict__ W3,
                    const float* __restrict__ b3,
                    float* __restrict__ out,
                    const int T)
{
    __shared__ float sS[TMAX];
    const int lane = threadIdx.x;   // 0..63, single wave
    const int j    = lane & 31;     // hidden unit owned by this lane (upper half replicates)

    for (int t = lane; t < T; t += 64)
        sS[t] = s_grid[t];
    __syncthreads();

    // ---- weights into registers (lane j holds column j of W1/W2, row j of W3) ----
    float w1[5];
    #pragma unroll
    for (int i = 0; i < 5; ++i) w1[i] = W1[i*32 + j];
    const float bb1 = b1[j];

    float w2[32];
    #pragma unroll
    for (int i = 0; i < 32; ++i) w2[i] = W2[i*32 + j];
    const float bb2 = b2[j];

    float w3[4], bb3[4], y[4];
    #pragma unroll
    for (int o = 0; o < 4; ++o) w3[o]  = W3[j*4 + o];
    #pragma unroll
    for (int o = 0; o < 4; ++o) bb3[o] = b3[o];
    #pragma unroll
    for (int o = 0; o < 4; ++o) y[o]   = y0[o];

    // row 0 = y0   (output is float32 — the reference's output dtype)
    if (lane == 0) {
        float4 r = make_float4(y[0], y[1], y[2], y[3]);
        *reinterpret_cast<float4*>(out) = r;
    }

    float s_cur = sS[0];

    for (int t = 0; t < T - 1; ++t) {
        const float s_nxt = sS[t + 1];
        const float hstep = s_nxt - s_cur;

        // one MLP eval: z=(z0..z3, s_cur) -> k[0..3]; k identical in all lanes after
        auto mlp = [&](float z0, float z1, float z2, float z3, float* k) {
            // layer 1: lane j computes h1[j]
            float a = bb1;
            a = fmaf(z0,    w1[0], a);
            a = fmaf(z1,    w1[1], a);
            a = fmaf(z2,    w1[2], a);
            a = fmaf(z3,    w1[3], a);
            a = fmaf(s_cur, w1[4], a);
            const float h1 = ftanh(a);

            // layer 2: gather all 32 h1 via readlane (SGPR broadcast), 4 accumulators
            const int hb = __float_as_int(h1);
            float a0 = bb2, a1 = 0.0f, a2 = 0.0f, a3 = 0.0f;
            #pragma unroll
            for (int i = 0; i < 32; i += 4) {
                a0 = fmaf(__int_as_float(__builtin_amdgcn_readlane(hb, i+0)), w2[i+0], a0);
                a1 = fmaf(__int_as_float(__builtin_amdgcn_readlane(hb, i+1)), w2[i+1], a1);
                a2 = fmaf(__int_as_float(__builtin_amdgcn_readlane(hb, i+2)), w2[i+2], a2);
                a3 = fmaf(__int_as_float(__builtin_amdgcn_readlane(hb, i+3)), w2[i+3], a3);
            }
            const float h2 = ftanh((a0 + a1) + (a2 + a3));

            // layer 3: per-lane partials, 5-stage ds_swizzle butterfly over the
            // 32-lane group. All lanes end with the full sum -> k wave-uniform.
            float p0 = h2 * w3[0];
            float p1 = h2 * w3[1];
            float p2 = h2 * w3[2];
            float p3 = h2 * w3[3];
            p0 = swz_add<0x041F>(p0); p1 = swz_add<0x041F>(p1);
            p2 = swz_add<0x041F>(p2); p3 = swz_add<0x041F>(p3);
            p0 = swz_add<0x081F>(p0); p1 = swz_add<0x081F>(p1);
            p2 = swz_add<0x081F>(p2); p3 = swz_add<0x081F>(p3);
            p0 = swz_add<0x101F>(p0); p1 = swz_add<0x101F>(p1);
            p2 = swz_add<0x101F>(p2); p3 = swz_add<0x101F>(p3);
            p0 = swz_add<0x201F>(p0); p1 = swz_add<0x201F>(p1);
            p2 = swz_add<0x201F>(p2); p3 = swz_add<0x201F>(p3);
            p0 = swz_add<0x401F>(p0); p1 = swz_add<0x401F>(p1);
            p2 = swz_add<0x401F>(p2); p3 = swz_add<0x401F>(p3);

            k[0] = fsigm(p0 + bb3[0]);
            k[1] = fsigm(p1 + bb3[1]);
            k[2] = fsigm(p2 + bb3[2]);
            k[3] = fsigm(p3 + bb3[3]);
        };

        float k[4], ks[4], zt[4];
        const float hh = 0.5f * hstep;

        mlp(y[0], y[1], y[2], y[3], k);                       // k1
        #pragma unroll
        for (int o = 0; o < 4; ++o) { ks[o] = k[o]; zt[o] = fmaf(hh, k[o], y[o]); }

        mlp(zt[0], zt[1], zt[2], zt[3], k);                   // k2
        #pragma unroll
        for (int o = 0; o < 4; ++o) { ks[o] = fmaf(2.0f, k[o], ks[o]); zt[o] = fmaf(hh, k[o], y[o]); }

        mlp(zt[0], zt[1], zt[2], zt[3], k);                   // k3
        #pragma unroll
        for (int o = 0; o < 4; ++o) { ks[o] = fmaf(2.0f, k[o], ks[o]); zt[o] = fmaf(hstep, k[o], y[o]); }

        mlp(zt[0], zt[1], zt[2], zt[3], k);                   // k4
        const float h6 = hstep * (1.0f / 6.0f);
        #pragma unroll
        for (int o = 0; o < 4; ++o) y[o] = fmaf(h6, ks[o] + k[o], y[o]);

        if (lane == 0) {
            float4 r = make_float4(y[0], y[1], y[2], y[3]);
            *reinterpret_cast<float4*>(out + 4*(t+1)) = r;
        }
        s_cur = s_nxt;
    }
}

extern "C" void kernel_launch(void* const* d_in, const int* in_sizes, int n_in,
                              void* d_out, int out_size, void* d_ws, size_t ws_size,
                              hipStream_t stream)
{
    const float* s_grid = (const float*)d_in[0];
    const float* y0     = (const float*)d_in[1];
    const float* W1     = (const float*)d_in[2];
    const float* b1     = (const float*)d_in[3];
    const float* W2     = (const float*)d_in[4];
    const float* b2     = (const float*)d_in[5];
    const float* W3     = (const float*)d_in[6];
    const float* b3     = (const float*)d_in[7];
    float* out = (float*)d_out;
    const int T = in_sizes[0];

    ode_rk4_kernel<<<dim3(1), dim3(64), 0, stream>>>(
        s_grid, y0, W1, b1, W2, b2, W3, b3, out, T);
}

// Round 5
// 6576.244 us; speedup vs baseline: 1.2741x; 1.2741x over previous
//
#include <hip/hip_runtime.h>
#include <hip/hip_bf16.h>

#define TMAX 4096

__device__ __forceinline__ float fexp2(float x){ return __builtin_amdgcn_exp2f(x); }
__device__ __forceinline__ float frcp (float x){ return __builtin_amdgcn_rcpf(x); }

// tanh(x) = 1 - 2/(exp2(2x*log2e)+1)   (saturates correctly for |x| large)
__device__ __forceinline__ float ftanh(float x){
    return 1.0f - 2.0f * frcp(fexp2(x * 2.8853900817779268f) + 1.0f);
}
// sigmoid(x) = 1/(1+exp2(-x*log2e))
__device__ __forceinline__ float fsigm(float x){
    return frcp(1.0f + fexp2(x * -1.4426950408889634f));
}

// x += dpp_perm(x) — VALU-latency cross-lane (rocPRIM-style gfx9 butterfly).
// 0xB1 = quad_perm [1,0,3,2] (xor1), 0x4E = quad_perm [2,3,0,1] (xor2),
// 0x141 = row_half_mirror (xor7), 0x140 = row_mirror (xor15).
// After all 4 stages every lane holds the sum over its 16-lane row.
template<int CTRL>
__device__ __forceinline__ float dpp_add(float x){
    int t = __builtin_amdgcn_update_dpp(0, __float_as_int(x), CTRL, 0xF, 0xF, true);
    return x + __int_as_float(t);
}

__global__ __launch_bounds__(64, 1)
void ode_rk4_kernel(const float* __restrict__ s_grid,
                    const float* __restrict__ y0,
                    const float* __restrict__ W1,
                    const float* __restrict__ b1,
                    const float* __restrict__ W2,
                    const float* __restrict__ b2,
                    const float* __restrict__ W3,
                    const float* __restrict__ b3,
                    float* __restrict__ out,
                    const int T)
{
    __shared__ float sS[TMAX];
    const int lane = threadIdx.x;   // 0..63, single wave
    const int j    = lane & 31;     // hidden unit owned by this lane (upper half replicates)

    for (int t = lane; t < T; t += 64)
        sS[t] = s_grid[t];
    __syncthreads();

    // ---- weights into registers (lane j holds column j of W1/W2, row j of W3) ----
    float w1[5];
    #pragma unroll
    for (int i = 0; i < 5; ++i) w1[i] = W1[i*32 + j];
    const float bb1 = b1[j];

    float w2[32];
    #pragma unroll
    for (int i = 0; i < 32; ++i) w2[i] = W2[i*32 + j];
    const float bb2 = b2[j];

    float w3[4], bb3[4], y[4];
    #pragma unroll
    for (int o = 0; o < 4; ++o) w3[o]  = W3[j*4 + o];
    #pragma unroll
    for (int o = 0; o < 4; ++o) bb3[o] = b3[o];
    #pragma unroll
    for (int o = 0; o < 4; ++o) y[o]   = y0[o];

    // row 0 = y0   (output dtype = reference output dtype = float32)
    if (lane == 0) {
        *reinterpret_cast<float4*>(out) = make_float4(y[0], y[1], y[2], y[3]);
    }

    float s_cur = sS[0];

    for (int t = 0; t < T - 1; ++t) {
        const float s_nxt = sS[t + 1];
        const float hstep = s_nxt - s_cur;

        // one MLP eval: z=(z0..z3, s_cur) -> k[0..3]; k identical in all lanes after
        auto mlp = [&](float z0, float z1, float z2, float z3, float* k) {
            // layer 1: lane j computes h1[j]; 2 parallel partial chains (depth 3)
            float ta = fmaf(z0, w1[0], bb1);
            ta = fmaf(z1, w1[1], ta);
            float tb = z2 * w1[2];
            tb = fmaf(z3,    w1[3], tb);
            tb = fmaf(s_cur, w1[4], tb);
            const float h1 = ftanh(ta + tb);

            // layer 2: gather all 32 h1 via readlane (SGPR broadcast), 4 accumulators
            const int hb = __float_as_int(h1);
            float a0 = bb2, a1 = 0.0f, a2 = 0.0f, a3 = 0.0f;
            #pragma unroll
            for (int i = 0; i < 32; i += 4) {
                a0 = fmaf(__int_as_float(__builtin_amdgcn_readlane(hb, i+0)), w2[i+0], a0);
                a1 = fmaf(__int_as_float(__builtin_amdgcn_readlane(hb, i+1)), w2[i+1], a1);
                a2 = fmaf(__int_as_float(__builtin_amdgcn_readlane(hb, i+2)), w2[i+2], a2);
                a3 = fmaf(__int_as_float(__builtin_amdgcn_readlane(hb, i+3)), w2[i+3], a3);
            }
            const float h2 = ftanh((a0 + a1) + (a2 + a3));

            // layer 3: per-lane partials, 4 DPP stages -> per-row sums (VALU
            // latency, no LDS path), then 2 readlanes per output combine the
            // two 16-unit rows. Result is wave-uniform in every lane.
            float p0 = h2 * w3[0];
            float p1 = h2 * w3[1];
            float p2 = h2 * w3[2];
            float p3 = h2 * w3[3];
            p0 = dpp_add<0xB1>(p0);  p1 = dpp_add<0xB1>(p1);
            p2 = dpp_add<0xB1>(p2);  p3 = dpp_add<0xB1>(p3);
            p0 = dpp_add<0x4E>(p0);  p1 = dpp_add<0x4E>(p1);
            p2 = dpp_add<0x4E>(p2);  p3 = dpp_add<0x4E>(p3);
            p0 = dpp_add<0x141>(p0); p1 = dpp_add<0x141>(p1);
            p2 = dpp_add<0x141>(p2); p3 = dpp_add<0x141>(p3);
            p0 = dpp_add<0x140>(p0); p1 = dpp_add<0x140>(p1);
            p2 = dpp_add<0x140>(p2); p3 = dpp_add<0x140>(p3);

            // lane 0 holds sum over units 0..15, lane 16 holds sum over 16..31
            const float s0a = __int_as_float(__builtin_amdgcn_readlane(__float_as_int(p0), 0));
            const float s0b = __int_as_float(__builtin_amdgcn_readlane(__float_as_int(p0), 16));
            const float s1a = __int_as_float(__builtin_amdgcn_readlane(__float_as_int(p1), 0));
            const float s1b = __int_as_float(__builtin_amdgcn_readlane(__float_as_int(p1), 16));
            const float s2a = __int_as_float(__builtin_amdgcn_readlane(__float_as_int(p2), 0));
            const float s2b = __int_as_float(__builtin_amdgcn_readlane(__float_as_int(p2), 16));
            const float s3a = __int_as_float(__builtin_amdgcn_readlane(__float_as_int(p3), 0));
            const float s3b = __int_as_float(__builtin_amdgcn_readlane(__float_as_int(p3), 16));

            k[0] = fsigm((bb3[0] + s0a) + s0b);
            k[1] = fsigm((bb3[1] + s1a) + s1b);
            k[2] = fsigm((bb3[2] + s2a) + s2b);
            k[3] = fsigm((bb3[3] + s3a) + s3b);
        };

        float k[4], ks[4], zt[4];
        const float hh = 0.5f * hstep;

        mlp(y[0], y[1], y[2], y[3], k);                       // k1
        #pragma unroll
        for (int o = 0; o < 4; ++o) { ks[o] = k[o]; zt[o] = fmaf(hh, k[o], y[o]); }

        mlp(zt[0], zt[1], zt[2], zt[3], k);                   // k2
        #pragma unroll
        for (int o = 0; o < 4; ++o) { ks[o] = fmaf(2.0f, k[o], ks[o]); zt[o] = fmaf(hh, k[o], y[o]); }

        mlp(zt[0], zt[1], zt[2], zt[3], k);                   // k3
        #pragma unroll
        for (int o = 0; o < 4; ++o) { ks[o] = fmaf(2.0f, k[o], ks[o]); zt[o] = fmaf(hstep, k[o], y[o]); }

        mlp(zt[0], zt[1], zt[2], zt[3], k);                   // k4
        const float h6 = hstep * (1.0f / 6.0f);
        #pragma unroll
        for (int o = 0; o < 4; ++o) y[o] = fmaf(h6, ks[o] + k[o], y[o]);

        if (lane == 0) {
            *reinterpret_cast<float4*>(out + 4*(t+1)) = make_float4(y[0], y[1], y[2], y[3]);
        }
        s_cur = s_nxt;
    }
}

extern "C" void kernel_launch(void* const* d_in, const int* in_sizes, int n_in,
                              void* d_out, int out_size, void* d_ws, size_t ws_size,
                              hipStream_t stream)
{
    const float* s_grid = (const float*)d_in[0];
    const float* y0     = (const float*)d_in[1];
    const float* W1     = (const float*)d_in[2];
    const float* b1     = (const float*)d_in[3];
    const float* W2     = (const float*)d_in[4];
    const float* b2     = (const float*)d_in[5];
    const float* W3     = (const float*)d_in[6];
    const float* b3     = (const float*)d_in[7];
    float* out = (float*)d_out;
    const int T = in_sizes[0];

    ode_rk4_kernel<<<dim3(1), dim3(64), 0, stream>>>(
        s_grid, y0, W1, b1, W2, b2, W3, b3, out, T);
}